// Round 8
// baseline (20.595 us; speedup 1.0000x reference)
//
#include <hip/hip_runtime.h>

// Problem constants (from setup_inputs): B=32, A=5, H=W=52, T=50
#define BB 32
#define AA 5
#define HH 52
#define WW 52
#define TT 50

#define HW (HH * WW)          // 2704
#define AHW (AA * HW)         // 13520
#define N1 (BB * AA * HW)     // 432640
#define N2 (BB * 2 * AA * HW) // 865280

#define CPT 4                  // cells/thread; HW%4==0 && WW%4==0 -> float4 IO
#define BLK 256
#define CPB (BLK * CPT)        // 1024 cells per block

// ---------------------------------------------------------------------------
// R8: LDS-instruction-throughput attack. Model (m134): loop LDS time/CU =
// waves/CU * 50 iters * cy/read. CPT=2 had 13.2 waves/CU * (b128+b32) = 4.9us;
// this CPT=4 variant has 7 waves/CU * b128-only = 1.75us:
//  - CPT=4 amortizes each broadcast truth read over 4 cells (float4 global IO)
//  - t06 derived in-register from tbox (drops the b32 read entirely)
//  - s_win read as one int4
// Structure otherwise identical to R7: grid (14,32)=448 blocks, single
// barrier, wave 0 builds truth cache + winner map (exact JAX argmax divide
// semantics) while waves 1..3 issue their global float4 loads early.
// ---------------------------------------------------------------------------
__global__ __launch_bounds__(BLK) void region_target_fused(
    const float* __restrict__ xy, const float* __restrict__ wh,
    const float* __restrict__ obj, const float* __restrict__ truth,
    const float* __restrict__ biases, float* __restrict__ out) {
    __shared__ float  s_truth[TT * 5];
    __shared__ float4 s_tbox[TT];     // (txl, txr, tyt, tyb)
    __shared__ int    s_win[CPB];     // winner t per local cell, -1 = none

    const int b = blockIdx.y;
    const int tid = threadIdx.x;
    const int cellbase = blockIdx.x * CPB;
    const int c0 = cellbase + tid * CPT;
    const bool active = c0 < AHW;

    // ---- issue global loads EARLY (before barrier) ----
    int a = 0, j = 0, i0 = 0, base2 = 0, base2h = 0, base1 = 0;
    float4 x4 = {0,0,0,0}, y4 = {0,0,0,0}, w4 = {0,0,0,0}, h4 = {0,0,0,0}, o4 = {0,0,0,0};
    float ba0 = 1.0f, ba1 = 1.0f;
    if (active) {
        a = c0 / HW;
        int rem = c0 - a * HW;
        j = rem / WW;
        i0 = rem - j * WW;                       // i0%4==0 -> float4 aligned
        base2  = ((b * 2 * AA + a) * HH + j) * WW + i0;   // x-half
        base2h = base2 + AA * HW;                          // y-half
        base1  = ((b * AA + a) * HH + j) * WW + i0;
        x4 = *(const float4*)(xy + base2);
        y4 = *(const float4*)(xy + base2h);
        w4 = *(const float4*)(wh + base2);
        h4 = *(const float4*)(wh + base2h);
        o4 = *(const float4*)(obj + base1);
        ba0 = biases[2 * a];
        ba1 = biases[2 * a + 1];
    }

    // ---- wave-0 prologue, single barrier ----
#pragma unroll
    for (int k = 0; k < CPT; ++k) s_win[tid + k * BLK] = -1;
    if (tid < TT) {
        const float* tr = truth + (b * TT + tid) * 5;
        float tx = tr[0], ty = tr[1], tw = tr[2], th = tr[3], tc = tr[4];
        s_truth[tid * 5 + 0] = tx;
        s_truth[tid * 5 + 1] = ty;
        s_truth[tid * 5 + 2] = tw;
        s_truth[tid * 5 + 3] = th;
        s_truth[tid * 5 + 4] = tc;
        s_tbox[tid] = make_float4(tx - tw * 0.5f, tx + tw * 0.5f,
                                  ty - th * 0.5f, ty + th * 0.5f);

        // argmax over anchors (exact divide, first max wins == jnp.argmax)
        float best = -1.0f;
        int n = 0;
#pragma unroll
        for (int aa = 0; aa < AA; ++aa) {
            float bw0 = biases[2 * aa] / (float)WW;      // uniform -> s_load
            float bh0 = biases[2 * aa + 1] / (float)HH;
            float il2 = fmaxf(-bw0 * 0.5f, -tw * 0.5f);
            float ir2 = fminf(bw0 * 0.5f, tw * 0.5f);
            float it2 = fmaxf(-bh0 * 0.5f, -th * 0.5f);
            float ib2 = fminf(bh0 * 0.5f, th * 0.5f);
            float ov2 = fmaxf(ir2 - il2, 0.0f) * fmaxf(ib2 - it2, 0.0f);
            float iou2 = ov2 / (bw0 * bh0 + tw * th - ov2);
            if (iou2 > best) { best = iou2; n = aa; }
        }
        int ti = (int)(tx * (float)WW);   // trunc == astype(int32) for tx>0
        int tj = (int)(ty * (float)HH);
        bool invalid_pos = (tx <= 0.0f) || (tx >= 1.0f) || (ty <= 0.0f) || (ty >= 1.0f);
        bool valid = !invalid_pos && ti >= 0 && tj >= 0 && ti < WW && tj < HH &&
                     (tw > 0.0f) && (th > 0.0f);
        if (valid) {
            int local = (n * HH + tj) * WW + ti - cellbase;
            if (local >= 0 && local < CPB) atomicMax(&s_win[local], tid);
        }
    }
    __syncthreads();
    if (!active) return;

    float xs[CPT]   = {x4.x, x4.y, x4.z, x4.w};
    float ys[CPT]   = {y4.x, y4.y, y4.z, y4.w};
    float hw_w[CPT] = {w4.x, w4.y, w4.z, w4.w};
    float hw_h[CPT] = {h4.x, h4.y, h4.z, h4.w};
    float os_[CPT]  = {o4.x, o4.y, o4.z, o4.w};

    float bxl[CPT], bxr[CPT], byt[CPT], byb[CPT], areap[CPT], m[CPT];
#pragma unroll
    for (int k = 0; k < CPT; ++k) {
        float bx = (xs[k] + (float)(i0 + k)) / (float)WW;   // exact ref order
        float by = (ys[k] + (float)j) / (float)HH;
        float bw = expf(hw_w[k]) * ba0 / (float)WW;
        float bh = expf(hw_h[k]) * ba1 / (float)HH;
        bxl[k] = bx - bw * 0.5f; bxr[k] = bx + bw * 0.5f;
        byt[k] = by - bh * 0.5f; byb[k] = by + bh * 0.5f;
        areap[k] = bw * bh;
        m[k] = -1e30f;
    }

    // division-free: iou>0.6 <=> 1.6*ov - 0.6*tarea > 0.6*areap (union>0).
    // t06 derived from tbox in-register (saves the b32 LDS read; +-ulp only
    // affects the compare, and a flip changes t_o_noobj by <= obj <= 1).
#pragma unroll 10
    for (int t = 0; t < TT; ++t) {
        float4 tb = s_tbox[t];
        float t06 = 0.6f * ((tb.y - tb.x) * (tb.w - tb.z));
#pragma unroll
        for (int k = 0; k < CPT; ++k) {
            float il = fmaxf(bxl[k], tb.x);
            float ir = fminf(bxr[k], tb.y);
            float it = fmaxf(byt[k], tb.z);
            float ib = fminf(byb[k], tb.w);
            float ov = fmaxf(ir - il, 0.0f) * fmaxf(ib - it, 0.0f);
            m[k] = fmaxf(m[k], fmaf(1.6f, ov, -t06));
        }
    }

    int4 win4 = *(const int4*)(&s_win[tid * CPT]);   // one ds_read_b128
    int wsel[CPT] = {win4.x, win4.y, win4.z, win4.w};

    float vxy0[CPT], vxy1[CPT], vwh0[CPT], vwh1[CPT], vwgt[CPT];
    float vobj[CPT], vnoobj[CPT], vlab[CPT];
#pragma unroll
    for (int k = 0; k < CPT; ++k) {
        bool ignorable = m[k] > 0.6f * areap[k];
        bool has = wsel[k] >= 0;
        if (has) {
            int wi = wsel[k];
            float stx  = s_truth[wi * 5 + 0];
            float sty  = s_truth[wi * 5 + 1];
            float stw  = s_truth[wi * 5 + 2];
            float sth  = s_truth[wi * 5 + 3];
            vxy0[k] = stx * (float)WW - (float)(i0 + k);
            vxy1[k] = sty * (float)HH - (float)j;
            vwh0[k] = logf(stw * (float)WW / ba0);
            vwh1[k] = logf(sth * (float)HH / ba1);
            vwgt[k] = 2.0f - stw * sth;
            float il = fmaxf(bxl[k], stx - stw * 0.5f);
            float ir = fminf(bxr[k], stx + stw * 0.5f);
            float it = fmaxf(byt[k], sty - sth * 0.5f);
            float ib = fminf(byb[k], sty + sth * 0.5f);
            float ov = fmaxf(ir - il, 0.0f) * fmaxf(ib - it, 0.0f);
            vobj[k] = ov / (areap[k] + stw * sth - ov);   // exact rescore divide
            vlab[k] = s_truth[wi * 5 + 4];
            vnoobj[k] = os_[k];
        } else {
            vxy0[k] = xs[k];  vxy1[k] = ys[k];
            vwh0[k] = hw_w[k]; vwh1[k] = hw_h[k];
            vwgt[k] = 0.0f;
            vobj[k] = os_[k];
            vlab[k] = -1.0f;
            vnoobj[k] = ignorable ? os_[k] : 0.0f;
        }
    }

    *(float4*)(out + base2)                   = make_float4(vxy0[0], vxy0[1], vxy0[2], vxy0[3]);
    *(float4*)(out + base2h)                  = make_float4(vxy1[0], vxy1[1], vxy1[2], vxy1[3]);
    *(float4*)(out + N2 + base2)              = make_float4(vwh0[0], vwh0[1], vwh0[2], vwh0[3]);
    *(float4*)(out + N2 + base2h)             = make_float4(vwh1[0], vwh1[1], vwh1[2], vwh1[3]);
    float4 wgt4 = make_float4(vwgt[0], vwgt[1], vwgt[2], vwgt[3]);
    *(float4*)(out + 2 * N2 + base2)          = wgt4;
    *(float4*)(out + 2 * N2 + base2h)         = wgt4;
    *(float4*)(out + 3 * N2 + base1)          = make_float4(vobj[0], vobj[1], vobj[2], vobj[3]);
    *(float4*)(out + 3 * N2 + N1 + base1)     = make_float4(vnoobj[0], vnoobj[1], vnoobj[2], vnoobj[3]);
    *(float4*)(out + 3 * N2 + 2 * N1 + base1) = make_float4(vlab[0], vlab[1], vlab[2], vlab[3]);
}

extern "C" void kernel_launch(void* const* d_in, const int* in_sizes, int n_in,
                              void* d_out, int out_size, void* d_ws, size_t ws_size,
                              hipStream_t stream) {
    const float* xy     = (const float*)d_in[0];
    const float* wh     = (const float*)d_in[1];
    const float* obj    = (const float*)d_in[2];
    const float* truth  = (const float*)d_in[3];
    const float* biases = (const float*)d_in[4];
    float* out = (float*)d_out;

    dim3 grid((AHW + CPB - 1) / CPB, BB);   // (14, 32) = 448 blocks
    region_target_fused<<<grid, BLK, 0, stream>>>(xy, wh, obj, truth, biases, out);
}